// Round 1
// 436.527 us; speedup vs baseline: 1.0245x; 1.0245x over previous
//
#include <hip/hip_runtime.h>
#include <cstdint>
#include <cstddef>

#define NS 512
#define NT 384
#define CZ 128

typedef __bf16 bf16x8 __attribute__((ext_vector_type(8)));
typedef __bf16 bf16x4 __attribute__((ext_vector_type(4)));
typedef float floatx16 __attribute__((ext_vector_type(16)));

// Workspace layouts (bf16 element units):
//   A_t[rb(96)][kc(64)][r(128)][e(8)]   panel = 65536 elems (128 rows, k=s)
//   B_t[pb(48)][kc(64)][r(256)][e(8)]   panel = 131072 elems
//   WT [e(128)][k(1024)]  k = (c>>4)*512 + d*16 + (c&15)
// k index = s;  kc = s>>3, e = s&7.  A-row m = i*32+c, B-row n = j*32+d.

// ---------------------------------------------------------------------------
__global__ __launch_bounds__(256) void prep_wout(const float* __restrict__ Wout,
                                                 __bf16* __restrict__ WT) {
  const int idx = blockIdx.x * 256 + threadIdx.x;  // 131072
  const int e = idx >> 10, kk = idx & 1023;
  const int round = kk >> 9, rem = kk & 511, d = rem >> 4, cp = rem & 15;
  const int c = round * 16 + cp;
  WT[idx] = (__bf16)Wout[(size_t)(c * 32 + d) * CZ + e];
}

// ---------------------------------------------------------------------------
__global__ __launch_bounds__(256) void prep_norm(const float* __restrict__ mask,
                                                 float* __restrict__ rnorm) {
  __shared__ float mi[512];
  const int i = blockIdx.x, t = threadIdx.x;
  mi[t]       = mask[(size_t)t * NT + i];
  mi[t + 256] = mask[(size_t)(t + 256) * NT + i];
  __syncthreads();
  for (int j = t; j < NT; j += 256) {
    float acc = 0.f;
#pragma unroll 4
    for (int s = 0; s < NS; ++s) acc += mi[s] * mask[(size_t)s * NT + j];
    rnorm[(size_t)i * NT + j] = 1.0f / (acc + 0.001f);
  }
}

// ---------------------------------------------------------------------------
// LN + projections, writing the tiled layouts. One wave per (i, 64-s chunk).
// LDS: single 16640 B pool; the bf16 transpose buffer T aliases the fp32 tile
// (single-wave block => program order makes the overwrite safe; an explicit
// __syncthreads() fences the type-punned overwrite against reordering).
// 16640 B/block -> 9 blocks/CU (was 21248 B -> 7).
// ---------------------------------------------------------------------------
__global__ __launch_bounds__(64) void ln_proj(const float* __restrict__ feat,
                                              const float* __restrict__ mask,
                                              const float* __restrict__ gamma,
                                              const float* __restrict__ beta,
                                              const float* __restrict__ Wa,
                                              const float* __restrict__ Wb,
                                              __bf16* __restrict__ Abf,
                                              __bf16* __restrict__ Bbf) {
  __shared__ __align__(16) float ubuf[64 * 65];    // fp32 tile, row stride 65
  __bf16* T = (__bf16*)ubuf;                       // alias: 32*72 bf16 = 4608 B
  const int bid = blockIdx.x;    // 3072
  const int i = bid >> 3;
  const int s0 = (bid & 7) << 6;
  const int lane = threadIdx.x;
  const int l31 = lane & 31, lh = lane >> 5;

  const int rsub = lane >> 4, cb = (lane & 15) * 4;
#pragma unroll
  for (int rr = 0; rr < 16; ++rr) {
    const int row = rr * 4 + rsub;
    const float4 v = *(const float4*)(feat + ((size_t)(s0 + row) * NT + i) * 64 + cb);
    ubuf[row * 65 + cb] = v.x; ubuf[row * 65 + cb + 1] = v.y;
    ubuf[row * 65 + cb + 2] = v.z; ubuf[row * 65 + cb + 3] = v.w;
  }
  __syncthreads();

  float x[64];
#pragma unroll
  for (int k = 0; k < 64; ++k) x[k] = ubuf[lane * 65 + k];  // lane = s-row

  float mu = 0.f;
#pragma unroll
  for (int k = 0; k < 64; ++k) mu += x[k];
  mu *= (1.0f / 64.0f);
  float var = 0.f;
#pragma unroll
  for (int k = 0; k < 64; ++k) { const float d = x[k] - mu; var += d * d; }
  var *= (1.0f / 64.0f);
  const float rstd = rsqrtf(var + 1e-5f);
#pragma unroll
  for (int k = 0; k < 64; ++k)
    x[k] = (x[k] - mu) * rstd * gamma[k] + beta[k];

  const float mv = mask[(size_t)(s0 + lane) * NT + i];

  // ---- projection A ----
  float acc[32];
#pragma unroll
  for (int c = 0; c < 32; ++c) acc[c] = 0.f;
#pragma unroll 8
  for (int k = 0; k < 64; ++k) {
    const float mk = x[k];
#pragma unroll
    for (int c = 0; c < 32; ++c) acc[c] = fmaf(mk, Wa[k * 32 + c], acc[c]);
  }
  __syncthreads();  // fence: all fp32 tile reads complete before T overwrites it
#pragma unroll
  for (int c = 0; c < 32; ++c) T[c * 72 + lane] = (__bf16)(acc[c] * mv);
  __syncthreads();
  {
    // dest: rb=i>>2, r=(i&3)*32+c, kc = s0/8 + kc_loc, e = s&7
    __bf16* dst = Abf + (size_t)(i >> 2) * 65536 + (size_t)(s0 >> 3) * 1024 +
                  (size_t)((i & 3) * 32) * 8;
#pragma unroll
    for (int q = 0; q < 4; ++q) {
      const bf16x8 v = *(const bf16x8*)(T + l31 * 72 + (q * 2 + lh) * 8);
      *(bf16x8*)(dst + (size_t)(q * 2 + lh) * 1024 + l31 * 8) = v;
    }
  }
  __syncthreads();

  // ---- projection B ----
#pragma unroll
  for (int c = 0; c < 32; ++c) acc[c] = 0.f;
#pragma unroll 8
  for (int k = 0; k < 64; ++k) {
    const float mk = x[k];
#pragma unroll
    for (int c = 0; c < 32; ++c) acc[c] = fmaf(mk, Wb[k * 32 + c], acc[c]);
  }
#pragma unroll
  for (int c = 0; c < 32; ++c) T[c * 72 + lane] = (__bf16)(acc[c] * mv);
  __syncthreads();
  {
    __bf16* dst = Bbf + (size_t)(i >> 3) * 131072 + (size_t)(s0 >> 3) * 2048 +
                  (size_t)((i & 7) * 32) * 8;
#pragma unroll
    for (int q = 0; q < 4; ++q) {
      const bf16x8 v = *(const bf16x8*)(T + l31 * 72 + (q * 2 + lh) * 8);
      *(bf16x8*)(dst + (size_t)(q * 2 + lh) * 2048 + l31 * 8) = v;
    }
  }
}

// ---------------------------------------------------------------------------
// Fused GEMM. Block 128x256, 4 waves (2x2), wave 64x128 (2x4 frags 32x32x16).
// 3-buffer staging pipeline, 2 tiles in flight, counted s_waitcnt vmcnt(6)
// (never drained to 0 in steady state), raw s_barriers (no implicit drain),
// setprio(1) around the MFMA cluster, XCD-aware block swizzle.
// Epilogue: 2 rounds over c-halves; P_half 32 pairs x 512 cd (d-major,
// padded); z accumulates.
// ---------------------------------------------------------------------------
__global__ __launch_bounds__(256) void opm_gemm(const __bf16* __restrict__ A,
                                                const __bf16* __restrict__ B,
                                                const __bf16* __restrict__ WT,
                                                const float* __restrict__ bout,
                                                const float* __restrict__ rnorm,
                                                float* __restrict__ out) {
  __shared__ __align__(16) __bf16 smem[36864];  // 73728 B = 3 x 12288-elem bufs
  // buffer o: As = smem + o (4 kc x 128 r x 8 e), Bs = As + 4096 (4x256x8)
  // P_half (epilogue alias): addr(p,d,c') = p*648 + d*20 + c'   (20736 elems)

  const int t = threadIdx.x, lane = t & 63, wid = t >> 6;
  const int wm = wid & 1, wn = wid >> 1;
  const int l31 = lane & 31, lh = lane >> 5;
  // XCD-aware swizzle: 4608 blocks = 8 XCDs x 576 contiguous logical ids.
  // Each XCD then walks 6 consecutive bn panels (B panels L2-resident).
  const int bid = (blockIdx.x & 7) * 576 + (blockIdx.x >> 3);
  const int bm = bid % 96, bn = bid / 96;

  const __bf16* Apan = A + (size_t)bm * 65536;
  const __bf16* Bpan = B + (size_t)bn * 131072;

  floatx16 acc[2][4];
#pragma unroll
  for (int fm = 0; fm < 2; ++fm)
#pragma unroll
    for (int fn = 0; fn < 4; ++fn)
#pragma unroll
      for (int q = 0; q < 16; ++q) acc[fm][fn][q] = 0.f;

#define STAGE(kt, OFF)                                                          \
  {                                                                             \
    __bf16* dst = smem + (OFF);                                                 \
    _Pragma("unroll")                                                           \
    for (int g2 = 0; g2 < 2; ++g2) {                                            \
      const int g = wid * 2 + g2;                                               \
      __builtin_amdgcn_global_load_lds(                                         \
          (const __attribute__((address_space(1))) void*)(Apan +                \
              (size_t)(kt) * 4096 + g * 512 + lane * 8),                        \
          (__attribute__((address_space(3))) void*)(dst + g * 512), 16, 0, 0);  \
    }                                                                           \
    _Pragma("unroll")                                                           \
    for (int g4 = 0; g4 < 4; ++g4) {                                            \
      const int g = wid * 4 + g4;                                               \
      __builtin_amdgcn_global_load_lds(                                         \
          (const __attribute__((address_space(1))) void*)(Bpan +                \
              (size_t)(kt) * 8192 + g * 512 + lane * 8),                        \
          (__attribute__((address_space(3))) void*)(dst + 4096 + g * 512),      \
          16, 0, 0);                                                            \
    }                                                                           \
  }

#define COMPUTE(OFF)                                                            \
  {                                                                             \
    const __bf16* As = smem + (OFF);                                            \
    const __bf16* Bs = As + 4096;                                               \
    __builtin_amdgcn_s_setprio(1);                                              \
    _Pragma("unroll")                                                           \
    for (int ks = 0; ks < 2; ++ks) {                                            \
      const int ck = ks * 2 + lh;                                               \
      bf16x8 af[2], bfv[4];                                                     \
      _Pragma("unroll")                                                         \
      for (int fm = 0; fm < 2; ++fm)                                            \
        af[fm] = *(const bf16x8*)(As + ck * 1024 + (wm * 64 + fm * 32 + l31) * 8); \
      _Pragma("unroll")                                                         \
      for (int fn = 0; fn < 4; ++fn)                                            \
        bfv[fn] = *(const bf16x8*)(Bs + ck * 2048 + (wn * 128 + fn * 32 + l31) * 8); \
      _Pragma("unroll")                                                         \
      for (int fm = 0; fm < 2; ++fm)                                            \
        _Pragma("unroll")                                                       \
        for (int fn = 0; fn < 4; ++fn)                                          \
          acc[fm][fn] = __builtin_amdgcn_mfma_f32_32x32x16_bf16(                \
              af[fm], bfv[fn], acc[fm][fn], 0, 0, 0);                           \
    }                                                                           \
    __builtin_amdgcn_s_setprio(0);                                              \
  }

  // Prologue: tiles 0 and 1 in flight (12 outstanding loads/wave).
  STAGE(0, 0);
  STAGE(1, 12288);

  unsigned o0 = 0, o1 = 12288, o2 = 24576;  // compute buf, next buf, stage tgt
  // Steady state (kt = 0..13): wait own tile-kt loads (leave 6 in flight),
  // stage tile kt+2 into the buffer everyone finished reading at kt-1
  // (separated by the trailing barrier of kt-1), barrier (=> ALL waves' tile-kt
  // loads landed), compute, barrier (protects buffer from next STAGE).
  for (int kt = 0; kt < 14; ++kt) {
    asm volatile("s_waitcnt vmcnt(6)");
    STAGE(kt + 2, o2);
    __builtin_amdgcn_s_barrier();
    __builtin_amdgcn_sched_barrier(0);
    COMPUTE(o0);
    __builtin_amdgcn_s_barrier();
    const unsigned tmp = o0; o0 = o1; o1 = o2; o2 = tmp;
  }
  // kt = 14: tile 15 still in flight.
  asm volatile("s_waitcnt vmcnt(6)");
  __builtin_amdgcn_s_barrier();
  __builtin_amdgcn_sched_barrier(0);
  COMPUTE(o0);
  __builtin_amdgcn_s_barrier();
  { const unsigned tmp = o0; o0 = o1; o1 = o2; o2 = tmp; }
  // kt = 15: final drain.
  asm volatile("s_waitcnt vmcnt(0)");
  __builtin_amdgcn_s_barrier();
  __builtin_amdgcn_sched_barrier(0);
  COMPUTE(o0);
  __builtin_amdgcn_s_barrier();
#undef STAGE
#undef COMPUTE

  // ---- epilogue: 2 rounds over c-halves ----
  floatx16 z;
#pragma unroll
  for (int q = 0; q < 16; ++q) z[q] = 0.f;
  const int e = wid * 32 + l31;

#pragma unroll
  for (int round = 0; round < 2; ++round) {
    __syncthreads();  // main-loop reads / previous GEMM2 reads complete
    // scatter regs r = round*8 + qp*4 + j  (c = 16*round + 8*qp + 4*lh + j)
#pragma unroll
    for (int fm = 0; fm < 2; ++fm)
#pragma unroll
      for (int fn = 0; fn < 4; ++fn) {
        const int p = (wm * 2 + fm) * 8 + wn * 4 + fn;
        __bf16* base = smem + p * 648 + l31 * 20 + lh * 4;
#pragma unroll
        for (int qp = 0; qp < 2; ++qp) {
          bf16x4 v;
#pragma unroll
          for (int j = 0; j < 4; ++j)
            v[j] = (__bf16)acc[fm][fn][round * 8 + qp * 4 + j];
          *(bf16x4*)(base + qp * 8) = v;
        }
      }
    __syncthreads();
    // GEMM2: z[p][e] += P_half[p][k] * WT[e][round*512 + k], K=512
    const __bf16* wrow = WT + (size_t)e * 1024 + round * 512 + lh * 8;
    const __bf16* prow = smem + l31 * 648 + lh * 8;
#pragma unroll 8
    for (int ks = 0; ks < 32; ++ks) {
      const bf16x8 pa = *(const bf16x8*)(prow + ks * 20);
      const bf16x8 wb = *(const bf16x8*)(wrow + ks * 16);
      z = __builtin_amdgcn_mfma_f32_32x32x16_bf16(pa, wb, z, 0, 0, 0);
    }
  }

  // out[i][j][e] = (z + bout[e]) * rnorm[i][j]
  const float be = bout[e];
#pragma unroll
  for (int r = 0; r < 16; ++r) {
    const int p = (r & 3) + 8 * (r >> 2) + 4 * lh;
    const int i = bm * 4 + (p >> 3), j = bn * 8 + (p & 7);
    const float rn = rnorm[(size_t)i * NT + j];
    out[((size_t)i * NT + j) * CZ + e] = (z[r] + be) * rn;
  }
}

// ---------------------------------------------------------------------------
extern "C" void kernel_launch(void* const* d_in, const int* in_sizes, int n_in,
                              void* d_out, int out_size, void* d_ws, size_t ws_size,
                              hipStream_t stream) {
  const float* feat  = (const float*)d_in[0];
  const float* mask  = (const float*)d_in[1];
  const float* gamma = (const float*)d_in[2];
  const float* beta  = (const float*)d_in[3];
  const float* Wa    = (const float*)d_in[4];
  const float* Wb    = (const float*)d_in[5];
  const float* Wout  = (const float*)d_in[6];
  const float* bout  = (const float*)d_in[7];
  float* out = (float*)d_out;

  char* ws = (char*)d_ws;
  const size_t AB_BYTES = (size_t)96 * 65536 * sizeof(__bf16);  // 12,582,912
  __bf16* Abf = (__bf16*)(ws);
  __bf16* Bbf = (__bf16*)(ws + AB_BYTES);
  __bf16* WT  = (__bf16*)(ws + 2 * AB_BYTES);
  float* rnorm = (float*)(ws + 2 * AB_BYTES + (size_t)CZ * 1024 * sizeof(__bf16));

  prep_wout<<<512, 256, 0, stream>>>(Wout, WT);
  prep_norm<<<NT, 256, 0, stream>>>(mask, rnorm);
  ln_proj<<<NT * (NS / 64), 64, 0, stream>>>(feat, mask, gamma, beta, Wa, Wb, Abf, Bbf);
  opm_gemm<<<96 * 48, 256, 0, stream>>>(Abf, Bbf, WT, bout, rnorm, out);
}